// Round 2
// baseline (430.927 us; speedup 1.0000x reference)
//
#include <hip/hip_runtime.h>

#define AANG 180
#define NN 256
#define BCH 12

#ifndef M_PI
#define M_PI 3.14159265358979323846
#endif

__device__ __forceinline__ int iclamp(int v, int lo, int hi) {
    return v < lo ? lo : (v > hi ? hi : v);
}

// ---------------- Radon v14 (R17): 2-band sequential tiling for 2 blocks/CU.
// Each (n,h,g) block processes its image half as TWO 64-row bands staged
// sequentially into a 66-row tile (68.4 KB LDS vs 159.7 KB). v13's per-
// (lane,angle) interval pruning makes the band split ~free: a ray only
// iterates the i's whose rows live in the current band, so the useful-sample
// set and per-sample math stay bit-identical; only fp summation order changes
// (band partials added). The 24 KB reduction buffer is eliminated by reusing
// the tile after compute. 2 blocks/CU -> 32 waves/CU (was 16): the latency-
// bound stall R16 exposed gets covered by TLP instead of ILP.
#define LSTR 259
#define LROWS 66

__global__ __launch_bounds__(1024, 8)
void radon_kernel(const float* __restrict__ x, float* __restrict__ partial,
                  const float* __restrict__ Wq, const float* __restrict__ Wk,
                  const float* __restrict__ Wv, float* __restrict__ WqT,
                  float* __restrict__ WkT, float* __restrict__ WvT) {
    __shared__ float tile[LROWS * LSTR];  // 68,376 B; reused as red[] at the end
    int blk = blockIdx.x;        // ((n*2)+h)*30 + g
    int tid = threadIdx.x;

    // --- wtrans prologue: 720 blocks x 45 elements = 32400 (exact) ---
    if (tid < 45) {
        int idx = blk * 45 + tid;
        int p = idx / AANG;
        int j = idx - p * AANG;
        int src = j * AANG + p;
        WqT[idx] = Wq[src];
        WkT[idx] = Wk[src];
        WvT[idx] = Wv[src];
    }

    int g = blk % 30;
    int t = blk / 30;
    int h = t & 1;
    int n = t >> 1;
    int lx = tid & 255;
    int qid = tid >> 8;
    const float* img = x + (size_t)n * NN * NN;
    float fx = (float)lx;

    float acc[6];
#pragma unroll
    for (int k = 0; k < 6; ++k) acc[k] = 0.0f;

    for (int b = 0; b < 2; ++b) {
        int bb = h * 2 + b;                 // global band 0..3
        int R0 = bb * 64 - 1;               // iy in [R0, R0+lrmax]
        unsigned lrmax = (bb == 3) ? 64u : 63u;
        int nrows = (int)lrmax + 2;         // tile rows = image rows R0..R0+lrmax+1
        float R0f = (float)R0;              // guard passes <=> sy in [R0f, R1f)
        float R1f = (float)(R0 + (int)lrmax + 1);

        if (b) __syncthreads();             // band0 compute done before overwrite
        for (int rr = qid; rr < nrows; rr += 4) {
            int gr = R0 + rr;
            bool rok = (gr >= 0) && (gr < NN);
            const float* row = img + gr * NN;
            int gc = lx - 1;
            tile[rr * LSTR + lx] = (rok && gc >= 0) ? row[gc] : 0.0f;
            if (lx < 3) {
                int gc2 = 255 + lx;
                tile[rr * LSTR + 256 + lx] = (rok && gc2 < NN) ? row[gc2] : 0.0f;
            }
        }
        __syncthreads();

        for (int k = 0; k < 6; ++k) {
            int a = g + k * 30;
            float th = (float)((double)a * (M_PI / 180.0));
            float c = cosf(th);
            float s = sinf(th);
            float kx = -128.0f * (c + s - 1.0f);
            float ky = -128.0f * (c - s - 1.0f);
            float xcon = c * fx + kx;    // sx = fma(s, fy, xcon)
            float dcon = -s * fx + ky;   // sy = fma(c, fy, dcon)

            // valid-row interval for THIS band (conservative ~1 slack; in-loop
            // guard enforces exactness)
            int ilo, ihi;
            if (fabsf(c) > 1e-6f) {
                float t0 = (R0f - dcon) / c;
                float t1 = (R1f - dcon) / c;
                float lo = fminf(t0, t1);
                float hi = fmaxf(t0, t1);
                ilo = max(0, (int)floorf(lo));
                ihi = min(256, (int)ceilf(hi) + 1);
            } else {  // only a == 90 deg: sy ~= dcon (constant over i)
                bool any = (dcon >= R0f - 1.0f) && (dcon < R1f + 1.0f);
                ilo = 0;
                ihi = any ? 256 : 0;
            }

            float a0 = 0.0f;
            for (int i = ilo + qid; i < ihi; i += 8) {
                // sample A (i < ihi guaranteed by loop condition)
                {
                    float fy = (float)i;
                    float sy = __builtin_fmaf(c, fy, dcon);
                    float sx = __builtin_fmaf(s, fy, xcon);
                    float iyf = floorf(sy), ixf = floorf(sx);
                    int lr = (int)iyf - R0, lc = (int)ixf + 1;
                    bool ok = ((unsigned)lr <= lrmax) & ((unsigned)lc <= 256u);
                    int ad = ok ? (lr * LSTR + lc) : 0;
                    float v00 = tile[ad], v01 = tile[ad + 1];
                    float v10 = tile[ad + LSTR], v11 = tile[ad + LSTR + 1];
                    float wy = sy - iyf, wx = sx - ixf;
                    float wx1 = 1.0f - wx, wy1 = 1.0f - wy;
                    float v = wy1 * (wx1 * v00 + wx * v01) + wy * (wx1 * v10 + wx * v11);
                    a0 += ok ? v : 0.0f;
                }
                // sample B (needs tail check i+4 < ihi)
                {
                    int i2 = i + 4;
                    float fy = (float)i2;
                    float sy = __builtin_fmaf(c, fy, dcon);
                    float sx = __builtin_fmaf(s, fy, xcon);
                    float iyf = floorf(sy), ixf = floorf(sx);
                    int lr = (int)iyf - R0, lc = (int)ixf + 1;
                    bool ok = (i2 < ihi) & ((unsigned)lr <= lrmax) & ((unsigned)lc <= 256u);
                    int ad = ok ? (lr * LSTR + lc) : 0;
                    float v00 = tile[ad], v01 = tile[ad + 1];
                    float v10 = tile[ad + LSTR], v11 = tile[ad + LSTR + 1];
                    float wy = sy - iyf, wx = sx - ixf;
                    float wx1 = 1.0f - wx, wy1 = 1.0f - wy;
                    float v = wy1 * (wx1 * v00 + wx * v01) + wy * (wx1 * v10 + wx * v11);
                    a0 += ok ? v : 0.0f;
                }
            }
            acc[k] += a0;
        }
    }

    // reduction: reuse tile as red[6][1024] (17,094 floats >= 6,144 needed)
    __syncthreads();
    float* red = tile;
#pragma unroll
    for (int k = 0; k < 6; ++k) red[k * 1024 + tid] = acc[k];
    __syncthreads();
    if (tid < 256) {
        size_t base = (((size_t)h * BCH + n) * AANG);
#pragma unroll
        for (int k = 0; k < 6; ++k) {
            float r = red[k * 1024 + tid] + red[k * 1024 + tid + 256] +
                      red[k * 1024 + tid + 512] + red[k * 1024 + tid + 768];
            partial[(base + (g + k * 30)) * NN + tid] = r;
        }
    }
}

// ---------------- QKV v7 (R13): 8 rows/block. Q,V row-major; Kt scatter-stores.
__global__ void qkv_kernel(const float* __restrict__ partial,
                           const float* __restrict__ WqT, const float* __restrict__ bq,
                           const float* __restrict__ WkT, const float* __restrict__ bk,
                           const float* __restrict__ WvT, const float* __restrict__ bv,
                           float* __restrict__ Q, float* __restrict__ Kt,
                           float* __restrict__ V) {
    __shared__ float srow_t[AANG][8];
    int blk = blockIdx.x;  // n*32 + i8
    int n = blk >> 5;
    int i0 = (blk & 31) * 8;
    int tid = threadIdx.x;  // 256
    const size_t HOFF = (size_t)BCH * AANG * NN;
    if (tid < AANG) {
        size_t idx = (((size_t)n) * AANG + tid) * NN + i0;
        float4 p0 = *(const float4*)&partial[idx];
        float4 p1 = *(const float4*)&partial[idx + 4];
        float4 q0 = *(const float4*)&partial[idx + HOFF];
        float4 q1 = *(const float4*)&partial[idx + HOFF + 4];
        srow_t[tid][0] = p0.x + q0.x;
        srow_t[tid][1] = p0.y + q0.y;
        srow_t[tid][2] = p0.z + q0.z;
        srow_t[tid][3] = p0.w + q0.w;
        srow_t[tid][4] = p1.x + q1.x;
        srow_t[tid][5] = p1.y + q1.y;
        srow_t[tid][6] = p1.z + q1.z;
        srow_t[tid][7] = p1.w + q1.w;
    }
    __syncthreads();
    if (tid < AANG) {
        int j = tid;
        float aq[8], ak[8], av[8];
        float bqv = bq[j], bkv = bk[j], bvv = bv[j];
        for (int r = 0; r < 8; ++r) { aq[r] = bqv; ak[r] = bkv; av[r] = bvv; }
#pragma unroll 4
        for (int p = 0; p < AANG; ++p) {
            float wq = WqT[p * AANG + j];
            float wk = WkT[p * AANG + j];
            float wv = WvT[p * AANG + j];
            float4 sv0 = *(const float4*)&srow_t[p][0];
            float4 sv1 = *(const float4*)&srow_t[p][4];
            aq[0] += sv0.x * wq; ak[0] += sv0.x * wk; av[0] += sv0.x * wv;
            aq[1] += sv0.y * wq; ak[1] += sv0.y * wk; av[1] += sv0.y * wv;
            aq[2] += sv0.z * wq; ak[2] += sv0.z * wk; av[2] += sv0.z * wv;
            aq[3] += sv0.w * wq; ak[3] += sv0.w * wk; av[3] += sv0.w * wv;
            aq[4] += sv1.x * wq; ak[4] += sv1.x * wk; av[4] += sv1.x * wv;
            aq[5] += sv1.y * wq; ak[5] += sv1.y * wk; av[5] += sv1.y * wv;
            aq[6] += sv1.z * wq; ak[6] += sv1.z * wk; av[6] += sv1.z * wv;
            aq[7] += sv1.w * wq; ak[7] += sv1.w * wk; av[7] += sv1.w * wv;
        }
        for (int r = 0; r < 8; ++r) {
            size_t qb = ((size_t)(n * NN + i0 + r)) * AANG + j;
            Q[qb] = aq[r];  // coalesced over j
            V[qb] = av[r];  // row-major, coalesced over j (PV reads coalesced)
        }
        size_t kb = ((size_t)(n * AANG + j)) * NN + i0;
        *(float4*)&Kt[kb]     = make_float4(ak[0], ak[1], ak[2], ak[3]);
        *(float4*)&Kt[kb + 4] = make_float4(ak[4], ak[5], ak[6], ak[7]);
    }
}

// ---------------- Attention v7 (R13): 8 rows/block; coalesced Kt/V streams. ----
__global__ void attn_kernel(const float* __restrict__ Q, const float* __restrict__ Kt,
                            const float* __restrict__ V, float* __restrict__ att_t) {
    __shared__ float qrow[8][AANG];
    __shared__ float prob[8][NN];
    __shared__ float wm[8][4], wsm[8][4];
    int blk = blockIdx.x;  // n*32 + i8
    int n = blk >> 5;
    int i0 = (blk & 31) * 8;
    int tid = threadIdx.x;  // 256: key index k
    int wid = tid >> 6;
    if (tid < AANG) {
#pragma unroll
        for (int r = 0; r < 8; ++r)
            qrow[r][tid] = Q[((size_t)(n * NN + i0 + r)) * AANG + tid];
    }
    __syncthreads();
    float d[8];
#pragma unroll
    for (int r = 0; r < 8; ++r) d[r] = 0.0f;
    const float* kcol = Kt + (size_t)n * AANG * NN + tid;  // lane k: coalesced
#pragma unroll 3
    for (int jj = 0; jj < AANG / 4; ++jj) {
        float kv0 = kcol[(size_t)(jj * 4 + 0) * NN];
        float kv1 = kcol[(size_t)(jj * 4 + 1) * NN];
        float kv2 = kcol[(size_t)(jj * 4 + 2) * NN];
        float kv3 = kcol[(size_t)(jj * 4 + 3) * NN];
#pragma unroll
        for (int r = 0; r < 8; ++r) {
            float4 qv = *(const float4*)&qrow[r][jj * 4];
            d[r] += qv.x * kv0;
            d[r] += qv.y * kv1;
            d[r] += qv.z * kv2;
            d[r] += qv.w * kv3;
        }
    }
    const float rs = 0.0745355992f;  // 1/sqrt(180)
    float l[8], m[8], e[8], s[8];
#pragma unroll
    for (int r = 0; r < 8; ++r) { l[r] = d[r] * rs; m[r] = l[r]; }
    for (int off = 32; off > 0; off >>= 1) {
#pragma unroll
        for (int r = 0; r < 8; ++r) m[r] = fmaxf(m[r], __shfl_xor(m[r], off));
    }
    if ((tid & 63) == 0) {
#pragma unroll
        for (int r = 0; r < 8; ++r) wm[r][wid] = m[r];
    }
    __syncthreads();
#pragma unroll
    for (int r = 0; r < 8; ++r) {
        float mx = fmaxf(fmaxf(wm[r][0], wm[r][1]), fmaxf(wm[r][2], wm[r][3]));
        e[r] = expf(l[r] - mx);
        s[r] = e[r];
    }
    for (int off = 32; off > 0; off >>= 1) {
#pragma unroll
        for (int r = 0; r < 8; ++r) s[r] += __shfl_xor(s[r], off);
    }
    if ((tid & 63) == 0) {
#pragma unroll
        for (int r = 0; r < 8; ++r) wsm[r][wid] = s[r];
    }
    __syncthreads();
#pragma unroll
    for (int r = 0; r < 8; ++r) {
        float dn = wsm[r][0] + wsm[r][1] + wsm[r][2] + wsm[r][3];
        prob[r][tid] = e[r] / dn;
    }
    __syncthreads();
    if (tid < AANG) {
        float a[8];
#pragma unroll
        for (int r = 0; r < 8; ++r) a[r] = 0.0f;
        const float* vcol = V + (size_t)n * NN * AANG + tid;  // lane j: coalesced
#pragma unroll 4
        for (int kk = 0; kk < NN / 4; ++kk) {
            float v0 = vcol[(size_t)(kk * 4 + 0) * AANG];
            float v1 = vcol[(size_t)(kk * 4 + 1) * AANG];
            float v2 = vcol[(size_t)(kk * 4 + 2) * AANG];
            float v3 = vcol[(size_t)(kk * 4 + 3) * AANG];
#pragma unroll
            for (int r = 0; r < 8; ++r) {
                float4 p4 = *(const float4*)&prob[r][kk * 4];
                a[r] += p4.x * v0;
                a[r] += p4.y * v1;
                a[r] += p4.z * v2;
                a[r] += p4.w * v3;
            }
        }
        size_t ob = ((size_t)(n * AANG + tid)) * NN + i0;
        *(float4*)&att_t[ob]     = make_float4(a[0], a[1], a[2], a[3]);
        *(float4*)&att_t[ob + 4] = make_float4(a[4], a[5], a[6], a[7]);
    }
}

// ---------------- Ramp filter v2: zero-padded scol, no boundary selects. ----
__global__ void filter_kernel(const float* __restrict__ att_t, float* __restrict__ filt) {
    __shared__ float scol[512];  // [128..383] = data, rest 0
    __shared__ float coef[128];
    int blk = blockIdx.x;  // n*AANG + a
    int tid = threadIdx.x;
    const float* src = &att_t[(size_t)blk * NN];
    scol[tid] = (tid >= 128) ? src[tid - 128] : 0.0f;
    scol[tid + 256] = (tid < 128) ? src[tid + 128] : 0.0f;
    if (tid < 128) {
        float d = (float)(2 * tid + 1);
        coef[tid] = -2.0f / ((float)(M_PI * M_PI) * d * d);
    }
    __syncthreads();
    const float* c = &scol[tid + 128];
    float acc = 0.5f * c[0];
#pragma unroll 4
    for (int m = 0; m < 128; ++m) {
        int d = 2 * m + 1;
        acc += coef[m] * (c[-d] + c[d]);
    }
    filt[(size_t)blk * NN + tid] = acc;
}

// ---------------- Backprojection v5: R15's v3 sampling (clamps, proven best)
// + float4 staging (2304 b128 copies/chunk instead of 9216 scalar). Values
// and accumulation order bit-identical to v3. ----
#define ACH 36
__global__ __launch_bounds__(1024)
void backproj_kernel(const float* __restrict__ filt, float* __restrict__ out) {
    __shared__ float cols[ACH][NN];
    __shared__ float cs[AANG], sn[AANG];
    int blk = blockIdx.x;  // n*64 + rg
    int n = blk >> 6;
    int rg = blk & 63;
    int tid = threadIdx.x;
    int col = tid & 255;
    int rslot = tid >> 8;
    int r = rg * 4 + rslot;
    if (tid < AANG) {
        float th = (float)((double)tid * (M_PI / 180.0));
        cs[tid] = cosf(th);
        sn[tid] = sinf(th);
    }
    float xr = (float)(r - 128);
    float yr = (float)(col - 128);
    float acc = 0.0f;
    const float* fb = filt + (size_t)n * AANG * NN;
    for (int ch = 0; ch < AANG / ACH; ++ch) {
        __syncthreads();
        // float4 staging: ACH*NN/4 = 2304 vector copies, q = idx>>6, c4 = idx&63
        for (int idx = tid; idx < ACH * (NN / 4); idx += 1024) {
            int q = idx >> 6;
            int c4 = idx & 63;
            float4 v = *(const float4*)&fb[(size_t)(ch * ACH + q) * NN + c4 * 4];
            *(float4*)&cols[q][c4 * 4] = v;
        }
        __syncthreads();
#pragma unroll 4
        for (int q = 0; q < ACH; ++q) {
            int aa = ch * ACH + q;
            float t = yr * cs[aa] - xr * sn[aa] + 128.0f;
            float i0f = floorf(t);
            int i0 = (int)i0f;
            float frac = t - i0f;
            int c0 = iclamp(i0, 0, NN - 1);
            int c1 = iclamp(i0 + 1, 0, NN - 1);
            float val = (1.0f - frac) * cols[q][c0] + frac * cols[q][c1];
            if (t >= 0.0f && t <= 255.0f) acc += val;
        }
    }
    bool inside = (xr * xr + yr * yr) <= 16384.0f;
    out[((size_t)(n * NN + r)) * NN + col] = inside ? acc * (float)(M_PI / 360.0) : 0.0f;
}

extern "C" void kernel_launch(void* const* d_in, const int* in_sizes, int n_in,
                              void* d_out, int out_size, void* d_ws, size_t ws_size,
                              hipStream_t stream) {
    const float* x  = (const float*)d_in[0];
    const float* Wq = (const float*)d_in[1];
    const float* bq = (const float*)d_in[2];
    const float* Wk = (const float*)d_in[3];
    const float* bk = (const float*)d_in[4];
    const float* Wv = (const float*)d_in[5];
    const float* bv = (const float*)d_in[6];
    float* out = (float*)d_out;
    float* ws = (float*)d_ws;

    const size_t SZ = (size_t)BCH * NN * AANG;
    float* P     = ws;           // partial[2][n][a][x]
    float* Q     = P + 2 * SZ;
    float* Kt    = Q + SZ;       // transposed: Kt[n][j][i] (attn reads coalesced)
    float* V     = Kt + SZ;      // row-major (attn PV reads coalesced)
    float* att_t = V + SZ;
    float* WqT   = att_t;        // alias: W-transposes dead before attn writes att_t
    float* WkT   = WqT + AANG * AANG;
    float* WvT   = WkT + AANG * AANG;
    float* filt  = P;            // alias: partials dead after qkv

    radon_kernel<<<BCH * 2 * 30, 1024, 0, stream>>>(x, P, Wq, Wk, Wv, WqT, WkT, WvT);
    qkv_kernel<<<BCH * (NN / 8), 256, 0, stream>>>(P, WqT, bq, WkT, bk, WvT, bv, Q, Kt, V);
    attn_kernel<<<BCH * (NN / 8), 256, 0, stream>>>(Q, Kt, V, att_t);
    filter_kernel<<<BCH * AANG, NN, 0, stream>>>(att_t, filt);
    backproj_kernel<<<BCH * (NN / 4), 1024, 0, stream>>>(filt, out);
}

// Round 3
// 409.807 us; speedup vs baseline: 1.0515x; 1.0515x over previous
//
#include <hip/hip_runtime.h>

#define AANG 180
#define NN 256
#define BCH 12

#ifndef M_PI
#define M_PI 3.14159265358979323846
#endif

__device__ __forceinline__ int iclamp(int v, int lo, int hi) {
    return v < lo ? lo : (v > hi ? hi : v);
}

// ---------------- Radon v15 (R18): consecutive-angle groups + pair-interleaved
// float2 tile + tight union intervals + 6-angle lockstep ILP.
//  * Block owns angles 6g..6g+5 (spread <=5 deg) so the per-band valid-i
//    intervals of all 6 angles nearly coincide: lockstep ILP over the UNION
//    interval visits ~1.05x the useful samples (v12 visited 2.7x).
//  * ptile[r][c] = {img[R0+r][c], img[R0+r+1][c]} (float2, 8B aligned): one
//    sample's 4 bilinear taps = 2 adjacent float2 loads -> ds_read(2)_b64,
//    HALF the LDS instructions of the old 4B-aligned ds_read2_b32 pairs.
//  * fx = tid>>2 (wave spans 16 detector cols -> small interval divergence),
//    sub = tid&3 strides i by 4 within the union interval.
//  * 64-row bands, 2 sequential stages per half; 65x259 float2 = 134.7 KB.
// Per-sample guard + fma/floor/lerp math bit-identical to v12/v14; only the
// visited-i set and fp summation order change.
#define LSTR2 259
#define NPAIRS 65

__global__ __launch_bounds__(1024, 4)
void radon_kernel(const float* __restrict__ x, float* __restrict__ partial,
                  const float* __restrict__ Wq, const float* __restrict__ Wk,
                  const float* __restrict__ Wv, float* __restrict__ WqT,
                  float* __restrict__ WkT, float* __restrict__ WvT) {
    __shared__ float2 ptile[NPAIRS * LSTR2];  // 134,680 B; reused as red[] at end
    int blk = blockIdx.x;        // ((n*2)+h)*30 + g
    int tid = threadIdx.x;

    // --- wtrans prologue: 720 blocks x 45 elements = 32400 (exact) ---
    if (tid < 45) {
        int idx = blk * 45 + tid;
        int p = idx / AANG;
        int j = idx - p * AANG;
        int src = j * AANG + p;
        WqT[idx] = Wq[src];
        WkT[idx] = Wk[src];
        WvT[idx] = Wv[src];
    }

    int g = blk % 30;            // angle group: a = 6g + k
    int t = blk / 30;
    int h = t & 1;
    int n = t >> 1;
    const float* img = x + (size_t)n * NN * NN;

    int fx_i = tid >> 2;         // detector column 0..255 (16 per wave)
    int sub = tid & 3;           // i-stride phase
    float fx = (float)fx_i;

    // per-angle constants (live across both bands)
    float c[6], s[6], xcon[6], dcon[6], acc[6];
#pragma unroll
    for (int k = 0; k < 6; ++k) {
        int a = 6 * g + k;
        float th = (float)((double)a * (M_PI / 180.0));
        c[k] = cosf(th);
        s[k] = sinf(th);
        float kx = -128.0f * (c[k] + s[k] - 1.0f);
        float ky = -128.0f * (c[k] - s[k] - 1.0f);
        xcon[k] = c[k] * fx + kx;    // sx = fma(s, fy, xcon)
        dcon[k] = -s[k] * fx + ky;   // sy = fma(c, fy, dcon)
        acc[k] = 0.0f;
    }

    for (int b = 0; b < 2; ++b) {
        int bb = h * 2 + b;                 // global band 0..3
        int R0 = bb * 64 - 1;               // valid iy in [R0, R0+lrmax]
        unsigned lrmax = (bb == 3) ? 64u : 63u;
        int npr = (int)lrmax + 1;           // pairs staged: lr = 0..lrmax
        float R0f = (float)R0;              // guard passes <=> sy in [R0f, R1f)
        float R1f = (float)(R0 + (int)lrmax + 1);

        if (b) __syncthreads();             // band0 compute done before restage
        // stage pairs: ptile[r*LSTR2+cc] = {img[R0+r][cc-1], img[R0+r+1][cc-1]}
        for (int idx = tid; idx < npr * LSTR2; idx += 1024) {
            int r = idx / LSTR2;
            int cc = idx - r * LSTR2;
            int gc = cc - 1;
            int gr0 = R0 + r;
            int gr1 = gr0 + 1;
            bool cok = (gc >= 0) && (gc < NN);
            float v0 = (cok && gr0 >= 0 && gr0 < NN) ? img[gr0 * NN + gc] : 0.0f;
            float v1 = (cok && gr1 >= 0 && gr1 < NN) ? img[gr1 * NN + gc] : 0.0f;
            ptile[idx] = make_float2(v0, v1);
        }
        __syncthreads();

        // union valid-i interval over the 6 (nearly parallel) angles
        int ilo = 256, ihi = 0;
#pragma unroll
        for (int k = 0; k < 6; ++k) {
            int lo_k, hi_k;
            if (fabsf(c[k]) > 1e-6f) {
                float t0 = (R0f - dcon[k]) / c[k];
                float t1 = (R1f - dcon[k]) / c[k];
                float lo = fminf(t0, t1);
                float hi = fmaxf(t0, t1);
                lo_k = max(0, (int)floorf(lo));
                hi_k = min(256, (int)ceilf(hi) + 1);
            } else {
                bool any = (dcon[k] >= R0f - 1.0f) && (dcon[k] < R1f + 1.0f);
                lo_k = 0;
                hi_k = any ? 256 : 0;
            }
            if (hi_k > lo_k) {
                ilo = min(ilo, lo_k);
                ihi = max(ihi, hi_k);
            }
        }

        for (int i = ilo + sub; i < ihi; i += 4) {
            float fy = (float)i;
#pragma unroll
            for (int k = 0; k < 6; ++k) {
                float sy = __builtin_fmaf(c[k], fy, dcon[k]);
                float sx = __builtin_fmaf(s[k], fy, xcon[k]);
                float iyf = floorf(sy), ixf = floorf(sx);
                int lr = (int)iyf - R0, lc = (int)ixf + 1;
                bool ok = ((unsigned)lr <= lrmax) & ((unsigned)lc <= 256u);
                int ad = ok ? (lr * LSTR2 + lc) : 0;
                float2 lo2 = ptile[ad];       // {v00, v10}
                float2 hi2 = ptile[ad + 1];   // {v01, v11}
                float v00 = lo2.x, v10 = lo2.y, v01 = hi2.x, v11 = hi2.y;
                float wy = sy - iyf, wx = sx - ixf;
                float wx1 = 1.0f - wx, wy1 = 1.0f - wy;
                float v = wy1 * (wx1 * v00 + wx * v01) + wy * (wx1 * v10 + wx * v11);
                acc[k] += ok ? v : 0.0f;
            }
        }
    }

    // reduction: reuse ptile as red[6][1024] (33,670 floats >= 6,144 needed)
    __syncthreads();
    float* red = (float*)ptile;
#pragma unroll
    for (int k = 0; k < 6; ++k) red[k * 1024 + fx_i * 4 + sub] = acc[k];
    __syncthreads();
    if (tid < 256) {
        size_t base = (((size_t)h * BCH + n) * AANG);
#pragma unroll
        for (int k = 0; k < 6; ++k) {
            float4 rv = *(const float4*)&red[k * 1024 + tid * 4];
            float r = rv.x + rv.y + rv.z + rv.w;
            partial[(base + (6 * g + k)) * NN + tid] = r;
        }
    }
}

// ---------------- QKV v7 (R13): 8 rows/block. Q,V row-major; Kt scatter-stores.
__global__ void qkv_kernel(const float* __restrict__ partial,
                           const float* __restrict__ WqT, const float* __restrict__ bq,
                           const float* __restrict__ WkT, const float* __restrict__ bk,
                           const float* __restrict__ WvT, const float* __restrict__ bv,
                           float* __restrict__ Q, float* __restrict__ Kt,
                           float* __restrict__ V) {
    __shared__ float srow_t[AANG][8];
    int blk = blockIdx.x;  // n*32 + i8
    int n = blk >> 5;
    int i0 = (blk & 31) * 8;
    int tid = threadIdx.x;  // 256
    const size_t HOFF = (size_t)BCH * AANG * NN;
    if (tid < AANG) {
        size_t idx = (((size_t)n) * AANG + tid) * NN + i0;
        float4 p0 = *(const float4*)&partial[idx];
        float4 p1 = *(const float4*)&partial[idx + 4];
        float4 q0 = *(const float4*)&partial[idx + HOFF];
        float4 q1 = *(const float4*)&partial[idx + HOFF + 4];
        srow_t[tid][0] = p0.x + q0.x;
        srow_t[tid][1] = p0.y + q0.y;
        srow_t[tid][2] = p0.z + q0.z;
        srow_t[tid][3] = p0.w + q0.w;
        srow_t[tid][4] = p1.x + q1.x;
        srow_t[tid][5] = p1.y + q1.y;
        srow_t[tid][6] = p1.z + q1.z;
        srow_t[tid][7] = p1.w + q1.w;
    }
    __syncthreads();
    if (tid < AANG) {
        int j = tid;
        float aq[8], ak[8], av[8];
        float bqv = bq[j], bkv = bk[j], bvv = bv[j];
        for (int r = 0; r < 8; ++r) { aq[r] = bqv; ak[r] = bkv; av[r] = bvv; }
#pragma unroll 4
        for (int p = 0; p < AANG; ++p) {
            float wq = WqT[p * AANG + j];
            float wk = WkT[p * AANG + j];
            float wv = WvT[p * AANG + j];
            float4 sv0 = *(const float4*)&srow_t[p][0];
            float4 sv1 = *(const float4*)&srow_t[p][4];
            aq[0] += sv0.x * wq; ak[0] += sv0.x * wk; av[0] += sv0.x * wv;
            aq[1] += sv0.y * wq; ak[1] += sv0.y * wk; av[1] += sv0.y * wv;
            aq[2] += sv0.z * wq; ak[2] += sv0.z * wk; av[2] += sv0.z * wv;
            aq[3] += sv0.w * wq; ak[3] += sv0.w * wk; av[3] += sv0.w * wv;
            aq[4] += sv1.x * wq; ak[4] += sv1.x * wk; av[4] += sv1.x * wv;
            aq[5] += sv1.y * wq; ak[5] += sv1.y * wk; av[5] += sv1.y * wv;
            aq[6] += sv1.z * wq; ak[6] += sv1.z * wk; av[6] += sv1.z * wv;
            aq[7] += sv1.w * wq; ak[7] += sv1.w * wk; av[7] += sv1.w * wv;
        }
        for (int r = 0; r < 8; ++r) {
            size_t qb = ((size_t)(n * NN + i0 + r)) * AANG + j;
            Q[qb] = aq[r];  // coalesced over j
            V[qb] = av[r];  // row-major, coalesced over j (PV reads coalesced)
        }
        size_t kb = ((size_t)(n * AANG + j)) * NN + i0;
        *(float4*)&Kt[kb]     = make_float4(ak[0], ak[1], ak[2], ak[3]);
        *(float4*)&Kt[kb + 4] = make_float4(ak[4], ak[5], ak[6], ak[7]);
    }
}

// ---------------- Attention v7 (R13): 8 rows/block; coalesced Kt/V streams. ----
__global__ void attn_kernel(const float* __restrict__ Q, const float* __restrict__ Kt,
                            const float* __restrict__ V, float* __restrict__ att_t) {
    __shared__ float qrow[8][AANG];
    __shared__ float prob[8][NN];
    __shared__ float wm[8][4], wsm[8][4];
    int blk = blockIdx.x;  // n*32 + i8
    int n = blk >> 5;
    int i0 = (blk & 31) * 8;
    int tid = threadIdx.x;  // 256: key index k
    int wid = tid >> 6;
    if (tid < AANG) {
#pragma unroll
        for (int r = 0; r < 8; ++r)
            qrow[r][tid] = Q[((size_t)(n * NN + i0 + r)) * AANG + tid];
    }
    __syncthreads();
    float d[8];
#pragma unroll
    for (int r = 0; r < 8; ++r) d[r] = 0.0f;
    const float* kcol = Kt + (size_t)n * AANG * NN + tid;  // lane k: coalesced
#pragma unroll 3
    for (int jj = 0; jj < AANG / 4; ++jj) {
        float kv0 = kcol[(size_t)(jj * 4 + 0) * NN];
        float kv1 = kcol[(size_t)(jj * 4 + 1) * NN];
        float kv2 = kcol[(size_t)(jj * 4 + 2) * NN];
        float kv3 = kcol[(size_t)(jj * 4 + 3) * NN];
#pragma unroll
        for (int r = 0; r < 8; ++r) {
            float4 qv = *(const float4*)&qrow[r][jj * 4];
            d[r] += qv.x * kv0;
            d[r] += qv.y * kv1;
            d[r] += qv.z * kv2;
            d[r] += qv.w * kv3;
        }
    }
    const float rs = 0.0745355992f;  // 1/sqrt(180)
    float l[8], m[8], e[8], s[8];
#pragma unroll
    for (int r = 0; r < 8; ++r) { l[r] = d[r] * rs; m[r] = l[r]; }
    for (int off = 32; off > 0; off >>= 1) {
#pragma unroll
        for (int r = 0; r < 8; ++r) m[r] = fmaxf(m[r], __shfl_xor(m[r], off));
    }
    if ((tid & 63) == 0) {
#pragma unroll
        for (int r = 0; r < 8; ++r) wm[r][wid] = m[r];
    }
    __syncthreads();
#pragma unroll
    for (int r = 0; r < 8; ++r) {
        float mx = fmaxf(fmaxf(wm[r][0], wm[r][1]), fmaxf(wm[r][2], wm[r][3]));
        e[r] = expf(l[r] - mx);
        s[r] = e[r];
    }
    for (int off = 32; off > 0; off >>= 1) {
#pragma unroll
        for (int r = 0; r < 8; ++r) s[r] += __shfl_xor(s[r], off);
    }
    if ((tid & 63) == 0) {
#pragma unroll
        for (int r = 0; r < 8; ++r) wsm[r][wid] = s[r];
    }
    __syncthreads();
#pragma unroll
    for (int r = 0; r < 8; ++r) {
        float dn = wsm[r][0] + wsm[r][1] + wsm[r][2] + wsm[r][3];
        prob[r][tid] = e[r] / dn;
    }
    __syncthreads();
    if (tid < AANG) {
        float a[8];
#pragma unroll
        for (int r = 0; r < 8; ++r) a[r] = 0.0f;
        const float* vcol = V + (size_t)n * NN * AANG + tid;  // lane j: coalesced
#pragma unroll 4
    for (int kk = 0; kk < NN / 4; ++kk) {
            float v0 = vcol[(size_t)(kk * 4 + 0) * AANG];
            float v1 = vcol[(size_t)(kk * 4 + 1) * AANG];
            float v2 = vcol[(size_t)(kk * 4 + 2) * AANG];
            float v3 = vcol[(size_t)(kk * 4 + 3) * AANG];
#pragma unroll
            for (int r = 0; r < 8; ++r) {
                float4 p4 = *(const float4*)&prob[r][kk * 4];
                a[r] += p4.x * v0;
                a[r] += p4.y * v1;
                a[r] += p4.z * v2;
                a[r] += p4.w * v3;
            }
        }
        size_t ob = ((size_t)(n * AANG + tid)) * NN + i0;
        *(float4*)&att_t[ob]     = make_float4(a[0], a[1], a[2], a[3]);
        *(float4*)&att_t[ob + 4] = make_float4(a[4], a[5], a[6], a[7]);
    }
}

// ---------------- Ramp filter v2: zero-padded scol, no boundary selects. ----
__global__ void filter_kernel(const float* __restrict__ att_t, float* __restrict__ filt) {
    __shared__ float scol[512];  // [128..383] = data, rest 0
    __shared__ float coef[128];
    int blk = blockIdx.x;  // n*AANG + a
    int tid = threadIdx.x;
    const float* src = &att_t[(size_t)blk * NN];
    scol[tid] = (tid >= 128) ? src[tid - 128] : 0.0f;
    scol[tid + 256] = (tid < 128) ? src[tid + 128] : 0.0f;
    if (tid < 128) {
        float d = (float)(2 * tid + 1);
        coef[tid] = -2.0f / ((float)(M_PI * M_PI) * d * d);
    }
    __syncthreads();
    const float* c = &scol[tid + 128];
    float acc = 0.5f * c[0];
#pragma unroll 4
    for (int m = 0; m < 128; ++m) {
        int d = 2 * m + 1;
        acc += coef[m] * (c[-d] + c[d]);
    }
    filt[(size_t)blk * NN + tid] = acc;
}

// ---------------- Backprojection v5: R15's v3 sampling (clamps, proven best)
// + float4 staging (2304 b128 copies/chunk instead of 9216 scalar). Values
// and accumulation order bit-identical to v3. ----
#define ACH 36
__global__ __launch_bounds__(1024)
void backproj_kernel(const float* __restrict__ filt, float* __restrict__ out) {
    __shared__ float cols[ACH][NN];
    __shared__ float cs[AANG], sn[AANG];
    int blk = blockIdx.x;  // n*64 + rg
    int n = blk >> 6;
    int rg = blk & 63;
    int tid = threadIdx.x;
    int col = tid & 255;
    int rslot = tid >> 8;
    int r = rg * 4 + rslot;
    if (tid < AANG) {
        float th = (float)((double)tid * (M_PI / 180.0));
        cs[tid] = cosf(th);
        sn[tid] = sinf(th);
    }
    float xr = (float)(r - 128);
    float yr = (float)(col - 128);
    float acc = 0.0f;
    const float* fb = filt + (size_t)n * AANG * NN;
    for (int ch = 0; ch < AANG / ACH; ++ch) {
        __syncthreads();
        // float4 staging: ACH*NN/4 = 2304 vector copies, q = idx>>6, c4 = idx&63
        for (int idx = tid; idx < ACH * (NN / 4); idx += 1024) {
            int q = idx >> 6;
            int c4 = idx & 63;
            float4 v = *(const float4*)&fb[(size_t)(ch * ACH + q) * NN + c4 * 4];
            *(float4*)&cols[q][c4 * 4] = v;
        }
        __syncthreads();
#pragma unroll 4
        for (int q = 0; q < ACH; ++q) {
            int aa = ch * ACH + q;
            float t = yr * cs[aa] - xr * sn[aa] + 128.0f;
            float i0f = floorf(t);
            int i0 = (int)i0f;
            float frac = t - i0f;
            int c0 = iclamp(i0, 0, NN - 1);
            int c1 = iclamp(i0 + 1, 0, NN - 1);
            float val = (1.0f - frac) * cols[q][c0] + frac * cols[q][c1];
            if (t >= 0.0f && t <= 255.0f) acc += val;
        }
    }
    bool inside = (xr * xr + yr * yr) <= 16384.0f;
    out[((size_t)(n * NN + r)) * NN + col] = inside ? acc * (float)(M_PI / 360.0) : 0.0f;
}

extern "C" void kernel_launch(void* const* d_in, const int* in_sizes, int n_in,
                              void* d_out, int out_size, void* d_ws, size_t ws_size,
                              hipStream_t stream) {
    const float* x  = (const float*)d_in[0];
    const float* Wq = (const float*)d_in[1];
    const float* bq = (const float*)d_in[2];
    const float* Wk = (const float*)d_in[3];
    const float* bk = (const float*)d_in[4];
    const float* Wv = (const float*)d_in[5];
    const float* bv = (const float*)d_in[6];
    float* out = (float*)d_out;
    float* ws = (float*)d_ws;

    const size_t SZ = (size_t)BCH * NN * AANG;
    float* P     = ws;           // partial[2][n][a][x]
    float* Q     = P + 2 * SZ;
    float* Kt    = Q + SZ;       // transposed: Kt[n][j][i] (attn reads coalesced)
    float* V     = Kt + SZ;      // row-major (attn PV reads coalesced)
    float* att_t = V + SZ;
    float* WqT   = att_t;        // alias: W-transposes dead before attn writes att_t
    float* WkT   = WqT + AANG * AANG;
    float* WvT   = WkT + AANG * AANG;
    float* filt  = P;            // alias: partials dead after qkv

    radon_kernel<<<BCH * 2 * 30, 1024, 0, stream>>>(x, P, Wq, Wk, Wv, WqT, WkT, WvT);
    qkv_kernel<<<BCH * (NN / 8), 256, 0, stream>>>(P, WqT, bq, WkT, bk, WvT, bv, Q, Kt, V);
    attn_kernel<<<BCH * (NN / 8), 256, 0, stream>>>(Q, Kt, V, att_t);
    filter_kernel<<<BCH * AANG, NN, 0, stream>>>(att_t, filt);
    backproj_kernel<<<BCH * (NN / 4), 1024, 0, stream>>>(filt, out);
}

// Round 4
// 399.088 us; speedup vs baseline: 1.0798x; 1.0269x over previous
//
#include <hip/hip_runtime.h>

#define AANG 180
#define NN 256
#define BCH 12

#ifndef M_PI
#define M_PI 3.14159265358979323846
#endif

__device__ __forceinline__ int iclamp(int v, int lo, int hi) {
    return v < lo ? lo : (v > hi ? hi : v);
}

// DPP row_ror add: v += rotate-within-16-lane-row(v, N). VALU only, no LDS pipe.
template <int CTRL>
__device__ __forceinline__ float dpp_add(float v) {
    int r = __builtin_amdgcn_update_dpp(0, __float_as_int(v), CTRL, 0xF, 0xF, true);
    return v + __int_as_float(r);
}

// ---------------- Radon v17 (R19): 90-degree pairing — ONE warp, TWO sinogram rows.
// Identity (exact in reals, verified vs reference formulas): sample at angle
// theta+90, output (x,y) == sample at angle theta, output (x~=y, y~=256-x).
// So the theta-warp W[y~][x~] gives BOTH:
//   sino(theta)[fx]        = sum over y~ of W[y~][fx]          (column sums)
//   sino(theta+90)[256-y~] = sum over x~ of W[y~][x~], y~=1..256 (row sums)
// Sample count HALVES. Blocks own 3 angles theta=3g..3g+2 in [0,89] (720 blocks,
// same scheduling as v15). Lane layout: fx = wv*16 + (l&15), sub = l>>4, so the
// 16 same-i lanes are exactly a DPP row -> row-partial = 4 VALU row_ror adds
// (no LDS), + one 4-lane ds_add_f32 atomic per wave-trip into rowsum[3][257].
// Wave-uniform lockstep intervals (min/max shfl) restore the aligned LDS access
// pattern v13-v15's per-lane starts destroyed. c=cos(theta)>=cos89 -> no 90-deg
// special case. Per-sample guard + fma/floor/lerp math bit-identical; the
// 90..179 half uses (c',s')=(-s,c) (ulp-level vs reference's own trig).
// Halves combine via the existing partial[2] + qkv sum (row-sums split across
// halves exactly like column-sums).
#define LSTR2 259
#define NPAIRS 65

__global__ __launch_bounds__(1024, 4)
void radon_kernel(const float* __restrict__ x, float* __restrict__ partial,
                  const float* __restrict__ Wq, const float* __restrict__ Wk,
                  const float* __restrict__ Wv, float* __restrict__ WqT,
                  float* __restrict__ WkT, float* __restrict__ WvT) {
    __shared__ float2 ptile[NPAIRS * LSTR2];  // 134,680 B
    __shared__ float rowsum[3][257];          // 3,084 B
    int blk = blockIdx.x;        // ((n*2)+h)*30 + g
    int tid = threadIdx.x;

    // --- wtrans prologue: 720 blocks x 45 elements = 32400 (exact) ---
    if (tid < 45) {
        int idx = blk * 45 + tid;
        int p = idx / AANG;
        int j = idx - p * AANG;
        int src = j * AANG + p;
        WqT[idx] = Wq[src];
        WkT[idx] = Wk[src];
        WvT[idx] = Wv[src];
    }

    int g = blk % 30;            // angle group: theta = 3g + k, k=0..2
    int t = blk / 30;
    int h = t & 1;
    int n = t >> 1;
    const float* img = x + (size_t)n * NN * NN;

    int l = tid & 63;            // lane in wave
    int wv = tid >> 6;           // wave 0..15
    int fxl = l & 15;            // fx within wave
    int sub = l >> 4;            // i-phase 0..3 (= DPP row id)
    int fx_i = wv * 16 + fxl;    // detector column 0..255
    float fx = (float)fx_i;

    if (tid < 3 * 257) ((float*)rowsum)[tid] = 0.0f;  // zeroed before 1st sync

    // per-angle constants (theta in [0,89] -> c >= cos(89deg) > 0.017)
    float c[3], s[3], xcon[3], dcon[3], acc[3];
#pragma unroll
    for (int k = 0; k < 3; ++k) {
        int a = 3 * g + k;
        float th = (float)((double)a * (M_PI / 180.0));
        c[k] = cosf(th);
        s[k] = sinf(th);
        float kx = -128.0f * (c[k] + s[k] - 1.0f);
        float ky = -128.0f * (c[k] - s[k] - 1.0f);
        xcon[k] = c[k] * fx + kx;    // sx = fma(s, fy, xcon)
        dcon[k] = -s[k] * fx + ky;   // sy = fma(c, fy, dcon)
        acc[k] = 0.0f;
    }

    for (int b = 0; b < 2; ++b) {
        int bb = h * 2 + b;                 // global band 0..3
        int R0 = bb * 64 - 1;               // valid floor(sy) in [R0, R0+lrmax]
        unsigned lrmax = (bb == 3) ? 64u : 63u;
        int npr = (int)lrmax + 1;           // pairs staged: lr = 0..lrmax
        float R0f = (float)R0;              // row guard passes <=> sy in [R0f, R1f)
        float R1f = (float)(R0 + (int)lrmax + 1);

        if (b) __syncthreads();             // band0 compute done before restage
        // stage pairs: ptile[r*LSTR2+cc] = {img[R0+r][cc-1], img[R0+r+1][cc-1]}
        for (int idx = tid; idx < npr * LSTR2; idx += 1024) {
            int r = idx / LSTR2;
            int cc = idx - r * LSTR2;
            int gc = cc - 1;
            int gr0 = R0 + r;
            int gr1 = gr0 + 1;
            bool cok = (gc >= 0) && (gc < NN);
            float v0 = (cok && gr0 >= 0 && gr0 < NN) ? img[gr0 * NN + gc] : 0.0f;
            float v1 = (cok && gr1 < NN) ? img[gr1 * NN + gc] : 0.0f;
            ptile[idx] = make_float2(v0, v1);
        }
        __syncthreads();

        // per-lane 3-angle union of valid-i intervals (conservative slack;
        // in-loop guard enforces exactness); i ranges over [0, 257)
        int ilo = 257, ihi = 0;
#pragma unroll
        for (int k = 0; k < 3; ++k) {
            float t0 = (R0f - dcon[k]) / c[k];   // c > 0 -> t0 < t1
            float t1 = (R1f - dcon[k]) / c[k];
            int lo_k = max(0, (int)floorf(t0));
            int hi_k = min(257, (int)ceilf(t1) + 1);
            if (hi_k > lo_k) {
                ilo = min(ilo, lo_k);
                ihi = max(ihi, hi_k);
            }
        }
        // wave-uniform interval -> lockstep loop (aligned LDS access, uniform
        // branch, and same-i DPP rows stay in step)
        for (int off = 1; off < 64; off <<= 1) {
            ilo = min(ilo, __shfl_xor(ilo, off));
            ihi = max(ihi, __shfl_xor(ihi, off));
        }

        for (int i = ilo + sub; i < ihi; i += 4) {
            float fy = (float)i;
            bool coli = (i < 256);   // column part sums y~ = 0..255
            bool rowi = (i >= 1);    // row part uses y~ = 1..256 (x = 256-y~)
#pragma unroll
            for (int k = 0; k < 3; ++k) {
                float sy = __builtin_fmaf(c[k], fy, dcon[k]);
                float sx = __builtin_fmaf(s[k], fy, xcon[k]);
                float iyf = floorf(sy), ixf = floorf(sx);
                int lr = (int)iyf - R0, lc = (int)ixf + 1;
                bool ok = ((unsigned)lr <= lrmax) & ((unsigned)lc <= 256u);
                int ad = ok ? (lr * LSTR2 + lc) : 0;
                float2 lo2 = ptile[ad];       // {v00, v10}
                float2 hi2 = ptile[ad + 1];   // {v01, v11}
                float wy = sy - iyf, wx = sx - ixf;
                float wx1 = 1.0f - wx, wy1 = 1.0f - wy;
                float v = wy1 * (wx1 * lo2.x + wx * hi2.x) +
                          wy  * (wx1 * lo2.y + wx * hi2.y);
                acc[k] += (ok && coli) ? v : 0.0f;
                // 16-fx row partial via DPP rotate-reduce (VALU only)
                float rv = (ok && rowi) ? v : 0.0f;
                rv = dpp_add<0x121>(rv);   // row_ror:1
                rv = dpp_add<0x122>(rv);   // row_ror:2
                rv = dpp_add<0x124>(rv);   // row_ror:4
                rv = dpp_add<0x128>(rv);   // row_ror:8
                if (fxl == 0) atomicAdd(&rowsum[k][i], rv);  // ds_add_f32, 4 lanes
            }
        }
    }

    __syncthreads();
    size_t base = (((size_t)h * BCH + n) * AANG);
    // column part: sum the 4 sub-phases (lanes l, l^16, l^32, l^48 share fx)
#pragma unroll
    for (int k = 0; k < 3; ++k) {
        acc[k] += __shfl_xor(acc[k], 16);
        acc[k] += __shfl_xor(acc[k], 32);
    }
    if (sub == 0) {
#pragma unroll
        for (int k = 0; k < 3; ++k)
            partial[(base + (3 * g + k)) * NN + fx_i] = acc[k];
    }
    // row part: sino(theta+90)[256-i] = rowsum[k][i], i = 1..256
    if (tid < 3 * 257) {
        int k = tid / 257;
        int i = tid - k * 257;
        if (i >= 1)
            partial[(base + (3 * g + k + 90)) * NN + (256 - i)] = rowsum[k][i];
    }
}

// ---------------- QKV v7 (R13): 8 rows/block. Q,V row-major; Kt scatter-stores.
__global__ void qkv_kernel(const float* __restrict__ partial,
                           const float* __restrict__ WqT, const float* __restrict__ bq,
                           const float* __restrict__ WkT, const float* __restrict__ bk,
                           const float* __restrict__ WvT, const float* __restrict__ bv,
                           float* __restrict__ Q, float* __restrict__ Kt,
                           float* __restrict__ V) {
    __shared__ float srow_t[AANG][8];
    int blk = blockIdx.x;  // n*32 + i8
    int n = blk >> 5;
    int i0 = (blk & 31) * 8;
    int tid = threadIdx.x;  // 256
    const size_t HOFF = (size_t)BCH * AANG * NN;
    if (tid < AANG) {
        size_t idx = (((size_t)n) * AANG + tid) * NN + i0;
        float4 p0 = *(const float4*)&partial[idx];
        float4 p1 = *(const float4*)&partial[idx + 4];
        float4 q0 = *(const float4*)&partial[idx + HOFF];
        float4 q1 = *(const float4*)&partial[idx + HOFF + 4];
        srow_t[tid][0] = p0.x + q0.x;
        srow_t[tid][1] = p0.y + q0.y;
        srow_t[tid][2] = p0.z + q0.z;
        srow_t[tid][3] = p0.w + q0.w;
        srow_t[tid][4] = p1.x + q1.x;
        srow_t[tid][5] = p1.y + q1.y;
        srow_t[tid][6] = p1.z + q1.z;
        srow_t[tid][7] = p1.w + q1.w;
    }
    __syncthreads();
    if (tid < AANG) {
        int j = tid;
        float aq[8], ak[8], av[8];
        float bqv = bq[j], bkv = bk[j], bvv = bv[j];
        for (int r = 0; r < 8; ++r) { aq[r] = bqv; ak[r] = bkv; av[r] = bvv; }
#pragma unroll 4
        for (int p = 0; p < AANG; ++p) {
            float wq = WqT[p * AANG + j];
            float wk = WkT[p * AANG + j];
            float wv = WvT[p * AANG + j];
            float4 sv0 = *(const float4*)&srow_t[p][0];
            float4 sv1 = *(const float4*)&srow_t[p][4];
            aq[0] += sv0.x * wq; ak[0] += sv0.x * wk; av[0] += sv0.x * wv;
            aq[1] += sv0.y * wq; ak[1] += sv0.y * wk; av[1] += sv0.y * wv;
            aq[2] += sv0.z * wq; ak[2] += sv0.z * wk; av[2] += sv0.z * wv;
            aq[3] += sv0.w * wq; ak[3] += sv0.w * wk; av[3] += sv0.w * wv;
            aq[4] += sv1.x * wq; ak[4] += sv1.x * wk; av[4] += sv1.x * wv;
            aq[5] += sv1.y * wq; ak[5] += sv1.y * wk; av[5] += sv1.y * wv;
            aq[6] += sv1.z * wq; ak[6] += sv1.z * wk; av[6] += sv1.z * wv;
            aq[7] += sv1.w * wq; ak[7] += sv1.w * wk; av[7] += sv1.w * wv;
        }
        for (int r = 0; r < 8; ++r) {
            size_t qb = ((size_t)(n * NN + i0 + r)) * AANG + j;
            Q[qb] = aq[r];  // coalesced over j
            V[qb] = av[r];  // row-major, coalesced over j (PV reads coalesced)
        }
        size_t kb = ((size_t)(n * AANG + j)) * NN + i0;
        *(float4*)&Kt[kb]     = make_float4(ak[0], ak[1], ak[2], ak[3]);
        *(float4*)&Kt[kb + 4] = make_float4(ak[4], ak[5], ak[6], ak[7]);
    }
}

// ---------------- Attention v7 (R13): 8 rows/block; coalesced Kt/V streams. ----
__global__ void attn_kernel(const float* __restrict__ Q, const float* __restrict__ Kt,
                            const float* __restrict__ V, float* __restrict__ att_t) {
    __shared__ float qrow[8][AANG];
    __shared__ float prob[8][NN];
    __shared__ float wm[8][4], wsm[8][4];
    int blk = blockIdx.x;  // n*32 + i8
    int n = blk >> 5;
    int i0 = (blk & 31) * 8;
    int tid = threadIdx.x;  // 256: key index k
    int wid = tid >> 6;
    if (tid < AANG) {
#pragma unroll
        for (int r = 0; r < 8; ++r)
            qrow[r][tid] = Q[((size_t)(n * NN + i0 + r)) * AANG + tid];
    }
    __syncthreads();
    float d[8];
#pragma unroll
    for (int r = 0; r < 8; ++r) d[r] = 0.0f;
    const float* kcol = Kt + (size_t)n * AANG * NN + tid;  // lane k: coalesced
#pragma unroll 3
    for (int jj = 0; jj < AANG / 4; ++jj) {
        float kv0 = kcol[(size_t)(jj * 4 + 0) * NN];
        float kv1 = kcol[(size_t)(jj * 4 + 1) * NN];
        float kv2 = kcol[(size_t)(jj * 4 + 2) * NN];
        float kv3 = kcol[(size_t)(jj * 4 + 3) * NN];
#pragma unroll
        for (int r = 0; r < 8; ++r) {
            float4 qv = *(const float4*)&qrow[r][jj * 4];
            d[r] += qv.x * kv0;
            d[r] += qv.y * kv1;
            d[r] += qv.z * kv2;
            d[r] += qv.w * kv3;
        }
    }
    const float rs = 0.0745355992f;  // 1/sqrt(180)
    float l[8], m[8], e[8], s[8];
#pragma unroll
    for (int r = 0; r < 8; ++r) { l[r] = d[r] * rs; m[r] = l[r]; }
    for (int off = 32; off > 0; off >>= 1) {
#pragma unroll
        for (int r = 0; r < 8; ++r) m[r] = fmaxf(m[r], __shfl_xor(m[r], off));
    }
    if ((tid & 63) == 0) {
#pragma unroll
        for (int r = 0; r < 8; ++r) wm[r][wid] = m[r];
    }
    __syncthreads();
#pragma unroll
    for (int r = 0; r < 8; ++r) {
        float mx = fmaxf(fmaxf(wm[r][0], wm[r][1]), fmaxf(wm[r][2], wm[r][3]));
        e[r] = expf(l[r] - mx);
        s[r] = e[r];
    }
    for (int off = 32; off > 0; off >>= 1) {
#pragma unroll
        for (int r = 0; r < 8; ++r) s[r] += __shfl_xor(s[r], off);
    }
    if ((tid & 63) == 0) {
#pragma unroll
        for (int r = 0; r < 8; ++r) wsm[r][wid] = s[r];
    }
    __syncthreads();
#pragma unroll
    for (int r = 0; r < 8; ++r) {
        float dn = wsm[r][0] + wsm[r][1] + wsm[r][2] + wsm[r][3];
        prob[r][tid] = e[r] / dn;
    }
    __syncthreads();
    if (tid < AANG) {
        float a[8];
#pragma unroll
        for (int r = 0; r < 8; ++r) a[r] = 0.0f;
        const float* vcol = V + (size_t)n * NN * AANG + tid;  // lane j: coalesced
#pragma unroll 4
        for (int kk = 0; kk < NN / 4; ++kk) {
            float v0 = vcol[(size_t)(kk * 4 + 0) * AANG];
            float v1 = vcol[(size_t)(kk * 4 + 1) * AANG];
            float v2 = vcol[(size_t)(kk * 4 + 2) * AANG];
            float v3 = vcol[(size_t)(kk * 4 + 3) * AANG];
#pragma unroll
            for (int r = 0; r < 8; ++r) {
                float4 p4 = *(const float4*)&prob[r][kk * 4];
                a[r] += p4.x * v0;
                a[r] += p4.y * v1;
                a[r] += p4.z * v2;
                a[r] += p4.w * v3;
            }
        }
        size_t ob = ((size_t)(n * AANG + tid)) * NN + i0;
        *(float4*)&att_t[ob]     = make_float4(a[0], a[1], a[2], a[3]);
        *(float4*)&att_t[ob + 4] = make_float4(a[4], a[5], a[6], a[7]);
    }
}

// ---------------- Ramp filter v2: zero-padded scol, no boundary selects. ----
__global__ void filter_kernel(const float* __restrict__ att_t, float* __restrict__ filt) {
    __shared__ float scol[512];  // [128..383] = data, rest 0
    __shared__ float coef[128];
    int blk = blockIdx.x;  // n*AANG + a
    int tid = threadIdx.x;
    const float* src = &att_t[(size_t)blk * NN];
    scol[tid] = (tid >= 128) ? src[tid - 128] : 0.0f;
    scol[tid + 256] = (tid < 128) ? src[tid + 128] : 0.0f;
    if (tid < 128) {
        float d = (float)(2 * tid + 1);
        coef[tid] = -2.0f / ((float)(M_PI * M_PI) * d * d);
    }
    __syncthreads();
    const float* c = &scol[tid + 128];
    float acc = 0.5f * c[0];
#pragma unroll 4
    for (int m = 0; m < 128; ++m) {
        int d = 2 * m + 1;
        acc += coef[m] * (c[-d] + c[d]);
    }
    filt[(size_t)blk * NN + tid] = acc;
}

// ---------------- Backprojection v5: R15's v3 sampling (clamps, proven best)
// + float4 staging (2304 b128 copies/chunk instead of 9216 scalar). Values
// and accumulation order bit-identical to v3. ----
#define ACH 36
__global__ __launch_bounds__(1024)
void backproj_kernel(const float* __restrict__ filt, float* __restrict__ out) {
    __shared__ float cols[ACH][NN];
    __shared__ float cs[AANG], sn[AANG];
    int blk = blockIdx.x;  // n*64 + rg
    int n = blk >> 6;
    int rg = blk & 63;
    int tid = threadIdx.x;
    int col = tid & 255;
    int rslot = tid >> 8;
    int r = rg * 4 + rslot;
    if (tid < AANG) {
        float th = (float)((double)tid * (M_PI / 180.0));
        cs[tid] = cosf(th);
        sn[tid] = sinf(th);
    }
    float xr = (float)(r - 128);
    float yr = (float)(col - 128);
    float acc = 0.0f;
    const float* fb = filt + (size_t)n * AANG * NN;
    for (int ch = 0; ch < AANG / ACH; ++ch) {
        __syncthreads();
        // float4 staging: ACH*NN/4 = 2304 vector copies, q = idx>>6, c4 = idx&63
        for (int idx = tid; idx < ACH * (NN / 4); idx += 1024) {
            int q = idx >> 6;
            int c4 = idx & 63;
            float4 v = *(const float4*)&fb[(size_t)(ch * ACH + q) * NN + c4 * 4];
            *(float4*)&cols[q][c4 * 4] = v;
        }
        __syncthreads();
#pragma unroll 4
        for (int q = 0; q < ACH; ++q) {
            int aa = ch * ACH + q;
            float t = yr * cs[aa] - xr * sn[aa] + 128.0f;
            float i0f = floorf(t);
            int i0 = (int)i0f;
            float frac = t - i0f;
            int c0 = iclamp(i0, 0, NN - 1);
            int c1 = iclamp(i0 + 1, 0, NN - 1);
            float val = (1.0f - frac) * cols[q][c0] + frac * cols[q][c1];
            if (t >= 0.0f && t <= 255.0f) acc += val;
        }
    }
    bool inside = (xr * xr + yr * yr) <= 16384.0f;
    out[((size_t)(n * NN + r)) * NN + col] = inside ? acc * (float)(M_PI / 360.0) : 0.0f;
}

extern "C" void kernel_launch(void* const* d_in, const int* in_sizes, int n_in,
                              void* d_out, int out_size, void* d_ws, size_t ws_size,
                              hipStream_t stream) {
    const float* x  = (const float*)d_in[0];
    const float* Wq = (const float*)d_in[1];
    const float* bq = (const float*)d_in[2];
    const float* Wk = (const float*)d_in[3];
    const float* bk = (const float*)d_in[4];
    const float* Wv = (const float*)d_in[5];
    const float* bv = (const float*)d_in[6];
    float* out = (float*)d_out;
    float* ws = (float*)d_ws;

    const size_t SZ = (size_t)BCH * NN * AANG;
    float* P     = ws;           // partial[2][n][a][x]
    float* Q     = P + 2 * SZ;
    float* Kt    = Q + SZ;       // transposed: Kt[n][j][i] (attn reads coalesced)
    float* V     = Kt + SZ;      // row-major (attn PV reads coalesced)
    float* att_t = V + SZ;
    float* WqT   = att_t;        // alias: W-transposes dead before attn writes att_t
    float* WkT   = WqT + AANG * AANG;
    float* WvT   = WkT + AANG * AANG;
    float* filt  = P;            // alias: partials dead after qkv

    radon_kernel<<<BCH * 2 * 30, 1024, 0, stream>>>(x, P, Wq, Wk, Wv, WqT, WkT, WvT);
    qkv_kernel<<<BCH * (NN / 8), 256, 0, stream>>>(P, WqT, bq, WkT, bk, WvT, bv, Q, Kt, V);
    attn_kernel<<<BCH * (NN / 8), 256, 0, stream>>>(Q, Kt, V, att_t);
    filter_kernel<<<BCH * AANG, NN, 0, stream>>>(att_t, filt);
    backproj_kernel<<<BCH * (NN / 4), 1024, 0, stream>>>(filt, out);
}